// Round 8
// baseline (6050.410 us; speedup 1.0000x reference)
//
#include <hip/hip_runtime.h>

#define TT 512
#define BB 64
#define HH 1024
#define EE 512
#define VV 50000
#define BBHH (BB*HH)
#define NBL 64          // blocks per layer
#define NBLK 128        // total persistent blocks

typedef __attribute__((ext_vector_type(8))) short bf16x8;
typedef __attribute__((ext_vector_type(4))) float f32x4;
typedef unsigned short us;

#define MFMA(a,b,c) __builtin_amdgcn_mfma_f32_16x16x32_bf16((a),(b),(c),0,0,0)
#define LDG(p) __hip_atomic_load((p), __ATOMIC_RELAXED, __HIP_MEMORY_SCOPE_AGENT)
// zone float index: [uh][ksw][m][nt][lane] x f32x4
#define ZI(uh,ksw,m,nt,ln) ((((((uh)*4+(ksw))*2+(m))*4+(nt))*64+(ln))*4)

__device__ inline us f2b(float f){
  unsigned u; __builtin_memcpy(&u, &f, 4);
  return (us)((u + 0x7FFFu + ((u >> 16) & 1u)) >> 16);
}
__device__ inline float sigmoidf_(float x){ return 1.0f / (1.0f + __expf(-x)); }
__device__ inline float tanhf_(float x){ float e = __expf(2.0f * x); return 1.0f - 2.0f / (e + 1.0f); }

__device__ inline bf16x8 pack8(float4 a, float4 b){
  bf16x8 r;
  r[0]=(short)f2b(a.x); r[1]=(short)f2b(a.y); r[2]=(short)f2b(a.z); r[3]=(short)f2b(a.w);
  r[4]=(short)f2b(b.x); r[5]=(short)f2b(b.y); r[6]=(short)f2b(b.z); r[7]=(short)f2b(b.w);
  return r;
}

// ---------------- cast fp32 -> bf16 ----------------
__global__ void cast_f2b(const float* __restrict__ src, us* __restrict__ dst, long n){
  long i = ((long)blockIdx.x * blockDim.x + threadIdx.x) * 4;
  long stride = (long)gridDim.x * blockDim.x * 4;
  for (; i + 3 < n; i += stride){
    float4 v = *reinterpret_cast<const float4*>(src + i);
    ushort4 r; r.x=f2b(v.x); r.y=f2b(v.y); r.z=f2b(v.z); r.w=f2b(v.w);
    *reinterpret_cast<ushort4*>(dst + i) = r;
  }
}

// ---------------- init: h0 fp32 [2,B,H] -> compact [j>>3][b][j&7] bf16 ----------------
__global__ void init_h(const float* __restrict__ h0,
                       us* __restrict__ h0ic, us* __restrict__ h1ic){
  int i = blockIdx.x * blockDim.x + threadIdx.x;   // b*HH + j
  int b = i >> 10, j = i & (HH - 1);
  int d = (((j >> 3) * BB) + b) * 8 + (j & 7);
  h0ic[d] = f2b(h0[i]);
  h1ic[d] = f2b(h0[BBHH + i]);
}

// ---------------- flag wait: one 64-lane load covers all 64 block-flags ----------------
__device__ __forceinline__ void wait64(const unsigned* __restrict__ f, unsigned e, int lane){
  unsigned a = LDG(f + lane);
  while (!__all((int)(a >= e))){
    __builtin_amdgcn_s_sleep(4);
    a = LDG(f + lane);
  }
}
// drain own sc1 stores, block barrier, raise flag
__device__ __forceinline__ void drain_flag(unsigned* __restrict__ fl, unsigned e){
  asm volatile("s_waitcnt vmcnt(0)" ::: "memory");
  __syncthreads();
  if (threadIdx.x == 0)
    __hip_atomic_store(fl, e, __ATOMIC_RELAXED, __HIP_MEMORY_SCOPE_AGENT);
}

// 64 blocks/layer, 512 threads, 8 waves = ks(K-quarter) x uh(unit-half of 16).
// A-row l16 -> (g=l16&3, u_local=2*(l16>>2)+m) within uh-half.
// D: row hi*4+i -> gate i, unit u_local=2hi+m; col l16 = batch-within-16, nt = batch/16.
// After reduce: thread (ks,uh,hi,l16) owns batch b=ks*16+l16, units j0+uh*8+2hi(+1).
__device__ void run_l0(int bid_l,
    const int* __restrict__ inputs, const float* __restrict__ c0,
    const us* __restrict__ emb_bf,
    const float* __restrict__ Wih0, const float* __restrict__ Whh0,
    const us* __restrict__ h0ic, us* __restrict__ hist0,
    float* __restrict__ hn, float* __restrict__ cn,
    unsigned* __restrict__ flags0, float* zone)
{
  const int tid = threadIdx.x, lane = tid & 63, wid = tid >> 6;
  const int l16 = lane & 15, hi = lane >> 4, kq = hi << 3;
  const int ks = wid & 3, uh = wid >> 2;
  const int j0 = bid_l * 16;

  bf16x8 wx[2][4], wh[2][8];
  #pragma unroll
  for (int m = 0; m < 2; ++m){
    const int g = l16 & 3;
    const int ug = j0 + uh * 8 + 2 * (l16 >> 2) + m;
    const float* rx = Wih0 + (size_t)(g * HH + ug) * EE;
    const float* rh = Whh0 + (size_t)(g * HH + ug) * HH;
    #pragma unroll
    for (int kk = 0; kk < 4; ++kk){
      int k0 = ks * 128 + kk * 32 + kq;
      wx[m][kk] = pack8(*(const float4*)(rx + k0), *(const float4*)(rx + k0 + 4));
    }
    #pragma unroll
    for (int kk = 0; kk < 8; ++kk){
      int k0 = ks * 256 + kk * 32 + kq;
      wh[m][kk] = pack8(*(const float4*)(rh + k0), *(const float4*)(rh + k0 + 4));
    }
  }

  const int b_own = ks * 16 + l16;
  const int u0    = j0 + uh * 8 + 2 * hi;
  float cs[2];
  #pragma unroll
  for (int m = 0; m < 2; ++m) cs[m] = c0[(size_t)b_own * HH + u0 + m];

  for (int t = 0; t < TT; ++t){
    f32x4 acc[2][4];
    #pragma unroll
    for (int m = 0; m < 2; ++m)
      #pragma unroll
      for (int nt = 0; nt < 4; ++nt) acc[m][nt] = (f32x4){0.f,0.f,0.f,0.f};

    // ---- emb x-part (dependency-free) ----
    {
      const us* xr[4];
      #pragma unroll
      for (int nt = 0; nt < 4; ++nt)
        xr[nt] = emb_bf + (size_t)inputs[t * BB + nt * 16 + l16] * EE;
      #pragma unroll
      for (int kk = 0; kk < 4; ++kk){
        const int kb = ks * 128 + kk * 32 + kq;
        #pragma unroll
        for (int nt = 0; nt < 4; ++nt){
          bf16x8 bf = *(const bf16x8*)(xr[nt] + kb);
          acc[0][nt] = MFMA(wx[0][kk], bf, acc[0][nt]);
          acc[1][nt] = MFMA(wx[1][kk], bf, acc[1][nt]);
        }
      }
    }

    // ---- drain h(t-1) publish (hidden under emb) + raise flag ----
    if (t > 0) drain_flag(flags0 + bid_l, (unsigned)t);
    // ---- wait all L0 flags >= t ----
    if (t > 0) wait64(flags0, (unsigned)t, lane);

    // ---- recurrent h-part ----
    {
      const us* hs = (t == 0) ? h0ic : hist0 + (size_t)(t - 1) * BBHH;
      #pragma unroll
      for (int kk = 0; kk < 8; ++kk){
        const us* p = hs + (size_t)(ks * 32 + kk * 4 + hi) * (BB * 8);
        #pragma unroll
        for (int nt = 0; nt < 4; ++nt){
          bf16x8 bf = *(const bf16x8*)(p + (nt * 16 + l16) * 8);
          acc[0][nt] = MFMA(wh[0][kk], bf, acc[0][nt]);
          acc[1][nt] = MFMA(wh[1][kk], bf, acc[1][nt]);
        }
      }
    }

    // ---- cross-wave K reduction (dense 16B/lane, conflict-free) ----
    #pragma unroll
    for (int m = 0; m < 2; ++m)
      #pragma unroll
      for (int nt = 0; nt < 4; ++nt)
        *(f32x4*)&zone[ZI(uh, ks, m, nt, lane)] = acc[m][nt];
    __syncthreads();
    f32x4 s[2];
    #pragma unroll
    for (int m = 0; m < 2; ++m){
      s[m] = (f32x4){0.f,0.f,0.f,0.f};
      #pragma unroll
      for (int kr = 0; kr < 4; ++kr)
        s[m] += *(f32x4*)&zone[ZI(uh, kr, m, ks, lane)];
    }

    // ---- cell update + publish ----
    float hv[2];
    #pragma unroll
    for (int m = 0; m < 2; ++m){
      float gi = sigmoidf_(s[m][0]), gf = sigmoidf_(s[m][1]);
      float gg = tanhf_(s[m][2]),    go = sigmoidf_(s[m][3]);
      cs[m] = gf * cs[m] + gi * gg;
      hv[m] = go * tanhf_(cs[m]);
    }
    unsigned w = (unsigned)f2b(hv[0]) | ((unsigned)f2b(hv[1]) << 16);
    __hip_atomic_store((unsigned*)(hist0 + (size_t)t * BBHH +
                        ((size_t)((2 * bid_l + uh) * BB + b_own)) * 8 + 2 * hi),
                       w, __ATOMIC_RELAXED, __HIP_MEMORY_SCOPE_AGENT);
    if (t == TT - 1){
      size_t o = (size_t)b_own * HH + u0;
      *reinterpret_cast<float2*>(hn + o) = make_float2(hv[0], hv[1]);
      *reinterpret_cast<float2*>(cn + o) = make_float2(cs[0], cs[1]);
    }
  }
  drain_flag(flags0 + bid_l, (unsigned)TT);
}

__device__ void run_l1(int bid_l,
    const float* __restrict__ c0,
    const float* __restrict__ Wih1, const float* __restrict__ Whh1,
    const us* __restrict__ h1ic, const us* __restrict__ hist0, us* __restrict__ hist1,
    const float* __restrict__ decW, const float* __restrict__ decb,
    float* __restrict__ dec_out, float* __restrict__ hn, float* __restrict__ cn,
    unsigned* __restrict__ flags0, unsigned* __restrict__ flags1, float* zone)
{
  const int tid = threadIdx.x, lane = tid & 63, wid = tid >> 6;
  const int l16 = lane & 15, hi = lane >> 4, kq = hi << 3;
  const int ks = wid & 3, uh = wid >> 2;
  const int j0 = bid_l * 16;

  bf16x8 wx[2][8], wh[2][8];
  #pragma unroll
  for (int m = 0; m < 2; ++m){
    const int g = l16 & 3;
    const int ug = j0 + uh * 8 + 2 * (l16 >> 2) + m;
    const float* rx = Wih1 + (size_t)(g * HH + ug) * HH;
    const float* rh = Whh1 + (size_t)(g * HH + ug) * HH;
    #pragma unroll
    for (int kk = 0; kk < 8; ++kk){
      int k0 = ks * 256 + kk * 32 + kq;
      wx[m][kk] = pack8(*(const float4*)(rx + k0), *(const float4*)(rx + k0 + 4));
      wh[m][kk] = pack8(*(const float4*)(rh + k0), *(const float4*)(rh + k0 + 4));
    }
  }

  const int b_own = ks * 16 + l16;
  const int u0    = j0 + uh * 8 + 2 * hi;
  float cs[2];
  #pragma unroll
  for (int m = 0; m < 2; ++m) cs[m] = c0[(size_t)BBHH + (size_t)b_own * HH + u0 + m];
  float pooldec = 0.f;
  const float dw0 = decW[u0], dw1 = decW[u0 + 1];

  for (int t = 0; t < TT; ++t){
    f32x4 acc[2][4];
    #pragma unroll
    for (int m = 0; m < 2; ++m)
      #pragma unroll
      for (int nt = 0; nt < 4; ++nt) acc[m][nt] = (f32x4){0.f,0.f,0.f,0.f};

    // ---- x-part from h0[t] (L0 runs ahead; wait usually satisfied) ----
    wait64(flags0, (unsigned)(t + 1), lane);
    {
      const us* xs = hist0 + (size_t)t * BBHH;
      #pragma unroll
      for (int kk = 0; kk < 8; ++kk){
        const us* p = xs + (size_t)(ks * 32 + kk * 4 + hi) * (BB * 8);
        #pragma unroll
        for (int nt = 0; nt < 4; ++nt){
          bf16x8 bf = *(const bf16x8*)(p + (nt * 16 + l16) * 8);
          acc[0][nt] = MFMA(wx[0][kk], bf, acc[0][nt]);
          acc[1][nt] = MFMA(wx[1][kk], bf, acc[1][nt]);
        }
      }
    }

    // ---- drain h1(t-1) publish (hidden under x-part) + raise flag1 ----
    if (t > 0) drain_flag(flags1 + bid_l, (unsigned)t);
    // ---- own-layer wait (round trip hidden by x-part) ----
    if (t > 0) wait64(flags1, (unsigned)t, lane);

    // ---- recurrent h1-part ----
    {
      const us* hs = (t == 0) ? h1ic : hist1 + (size_t)(t - 1) * BBHH;
      #pragma unroll
      for (int kk = 0; kk < 8; ++kk){
        const us* p = hs + (size_t)(ks * 32 + kk * 4 + hi) * (BB * 8);
        #pragma unroll
        for (int nt = 0; nt < 4; ++nt){
          bf16x8 bf = *(const bf16x8*)(p + (nt * 16 + l16) * 8);
          acc[0][nt] = MFMA(wh[0][kk], bf, acc[0][nt]);
          acc[1][nt] = MFMA(wh[1][kk], bf, acc[1][nt]);
        }
      }
    }

    // ---- reduce ----
    #pragma unroll
    for (int m = 0; m < 2; ++m)
      #pragma unroll
      for (int nt = 0; nt < 4; ++nt)
        *(f32x4*)&zone[ZI(uh, ks, m, nt, lane)] = acc[m][nt];
    __syncthreads();
    f32x4 s[2];
    #pragma unroll
    for (int m = 0; m < 2; ++m){
      s[m] = (f32x4){0.f,0.f,0.f,0.f};
      #pragma unroll
      for (int kr = 0; kr < 4; ++kr)
        s[m] += *(f32x4*)&zone[ZI(uh, kr, m, ks, lane)];
    }

    // ---- cell + publish ----
    float hv[2];
    #pragma unroll
    for (int m = 0; m < 2; ++m){
      float gi = sigmoidf_(s[m][0]), gf = sigmoidf_(s[m][1]);
      float gg = tanhf_(s[m][2]),    go = sigmoidf_(s[m][3]);
      cs[m] = gf * cs[m] + gi * gg;
      hv[m] = go * tanhf_(cs[m]);
    }
    unsigned w = (unsigned)f2b(hv[0]) | ((unsigned)f2b(hv[1]) << 16);
    __hip_atomic_store((unsigned*)(hist1 + (size_t)t * BBHH +
                        ((size_t)((2 * bid_l + uh) * BB + b_own)) * 8 + 2 * hi),
                       w, __ATOMIC_RELAXED, __HIP_MEMORY_SCOPE_AGENT);
    pooldec += hv[0] * dw0 + hv[1] * dw1;
    if (t == TT - 1){
      size_t o = (size_t)BBHH + (size_t)b_own * HH + u0;
      *reinterpret_cast<float2*>(hn + o) = make_float2(hv[0], hv[1]);
      *reinterpret_cast<float2*>(cn + o) = make_float2(cs[0], cs[1]);
    }
  }

  // ---- decode ----
  pooldec += __shfl_xor(pooldec, 16);
  pooldec += __shfl_xor(pooldec, 32);
  if (lane < 16){
    float contrib = pooldec * (1.0f / (float)TT);
    if (bid_l == 0 && uh == 0) contrib += decb[0];
    atomicAdd(&dec_out[ks * 16 + lane], contrib);
  }
}

__global__ __launch_bounds__(512, 2) void lstm_persist(
    const int* __restrict__ inputs, const float* __restrict__ c0,
    const us* __restrict__ emb_bf,
    const float* __restrict__ Wih0, const float* __restrict__ Whh0,
    const float* __restrict__ Wih1, const float* __restrict__ Whh1,
    const us* __restrict__ h0ic, const us* __restrict__ h1ic,
    us* __restrict__ hist0, us* __restrict__ hist1,
    const float* __restrict__ decW, const float* __restrict__ decb,
    float* __restrict__ dec_out, float* __restrict__ hn, float* __restrict__ cn,
    unsigned* __restrict__ flags)
{
  __shared__ float zone[2 * 4 * 2 * 4 * 64 * 4];   // 64 KB
  unsigned* flags0 = flags;
  unsigned* flags1 = flags + 64;
  int bid = blockIdx.x;
  if (bid < NBL){
    run_l0(bid, inputs, c0, emb_bf, Wih0, Whh0, h0ic, hist0,
           hn, cn, flags0, zone);
  } else {
    run_l1(bid - NBL, c0, Wih1, Whh1, h1ic, hist0, hist1, decW, decb,
           dec_out, hn, cn, flags0, flags1, zone);
  }
}

extern "C" void kernel_launch(void* const* d_in, const int* in_sizes, int n_in,
                              void* d_out, int out_size, void* d_ws, size_t ws_size,
                              hipStream_t stream){
  const int*   inputs = (const int*)d_in[0];
  const float* h0     = (const float*)d_in[1];
  const float* c0     = (const float*)d_in[2];
  const float* emb    = (const float*)d_in[3];
  const float* Wih0   = (const float*)d_in[4];
  const float* Whh0   = (const float*)d_in[5];
  const float* Wih1   = (const float*)d_in[6];
  const float* Whh1   = (const float*)d_in[7];
  const float* decW   = (const float*)d_in[8];
  const float* decb   = (const float*)d_in[9];

  char* ws = (char*)d_ws;
  size_t off = 0;
  auto alloc = [&](size_t bytes) -> void* {
    void* p = ws + off;
    off += (bytes + 255) & ~(size_t)255;
    return p;
  };
  us* emb_bf = (us*)alloc((size_t)VV * EE * 2);        // 51.2 MB
  us* hist0  = (us*)alloc((size_t)TT * BBHH * 2);      // 64 MB
  us* hist1  = (us*)alloc((size_t)TT * BBHH * 2);      // 64 MB
  us* h0ic   = (us*)alloc((size_t)BBHH * 2);
  us* h1ic   = (us*)alloc((size_t)BBHH * 2);
  unsigned* flags = (unsigned*)alloc((size_t)128 * 4);

  float* out = (float*)d_out;            // decoded [B]
  float* hn  = out + BB;                 // [2,B,H]
  float* cn  = out + BB + 2 * BBHH;      // [2,B,H]

  hipMemsetAsync(flags, 0, 128 * 4, stream);
  hipMemsetAsync(out, 0, BB * 4, stream);

  cast_f2b<<<2048, 256, 0, stream>>>(emb, emb_bf, (long)VV * EE);
  init_h<<<BBHH / 256, 256, 0, stream>>>(h0, h0ic, h1ic);

  lstm_persist<<<NBLK, 512, 0, stream>>>(inputs, c0, emb_bf,
                                         Wih0, Whh0, Wih1, Whh1,
                                         h0ic, h1ic, hist0, hist1,
                                         decW, decb, out, hn, cn, flags);
}

// Round 9
// 4490.923 us; speedup vs baseline: 1.3473x; 1.3473x over previous
//
#include <hip/hip_runtime.h>

#define TT 512
#define BB 64
#define HH 1024
#define EE 512
#define VV 50000
#define BBHH (BB*HH)
#define NBL 128
#define NBLK 256

typedef __attribute__((ext_vector_type(8))) short bf16x8;
typedef __attribute__((ext_vector_type(4))) float f32x4;
typedef unsigned short us;

#define MFMA(a,b,c) __builtin_amdgcn_mfma_f32_16x16x32_bf16((a),(b),(c),0,0,0)
#define LDG(p) __hip_atomic_load((p), __ATOMIC_RELAXED, __HIP_MEMORY_SCOPE_AGENT)

__device__ inline us f2b(float f){
  unsigned u; __builtin_memcpy(&u, &f, 4);
  return (us)((u + 0x7FFFu + ((u >> 16) & 1u)) >> 16);
}
__device__ inline float sigmoidf_(float x){ return 1.0f / (1.0f + __expf(-x)); }
__device__ inline float tanhf_(float x){ float e = __expf(2.0f * x); return 1.0f - 2.0f / (e + 1.0f); }

__device__ inline bf16x8 pack8(float4 a, float4 b){
  bf16x8 r;
  r[0]=(short)f2b(a.x); r[1]=(short)f2b(a.y); r[2]=(short)f2b(a.z); r[3]=(short)f2b(a.w);
  r[4]=(short)f2b(b.x); r[5]=(short)f2b(b.y); r[6]=(short)f2b(b.z); r[7]=(short)f2b(b.w);
  return r;
}

// ---------------- cast fp32 -> bf16 ----------------
__global__ void cast_f2b(const float* __restrict__ src, us* __restrict__ dst, long n){
  long i = ((long)blockIdx.x * blockDim.x + threadIdx.x) * 4;
  long stride = (long)gridDim.x * blockDim.x * 4;
  for (; i + 3 < n; i += stride){
    float4 v = *reinterpret_cast<const float4*>(src + i);
    ushort4 r; r.x=f2b(v.x); r.y=f2b(v.y); r.z=f2b(v.z); r.w=f2b(v.w);
    *reinterpret_cast<ushort4*>(dst + i) = r;
  }
}

// ---------------- init: h0 fp32 [2,B,H] -> compact [j>>3][b][j&7] bf16 ----------------
__global__ void init_h(const float* __restrict__ h0,
                       us* __restrict__ h0ic, us* __restrict__ h1ic){
  int i = blockIdx.x * blockDim.x + threadIdx.x;   // b*HH + j
  int b = i >> 10, j = i & (HH - 1);
  int d = (((j >> 3) * BB) + b) * 8 + (j & 7);
  h0ic[d] = f2b(h0[i]);
  h1ic[d] = f2b(h0[BBHH + i]);
}

// ---------------- flag poll over 128 entries (2 loads/lane) ----------------
__device__ __forceinline__ void wait128(const unsigned* __restrict__ f, unsigned e, int lane){
  unsigned a = LDG(f + lane), b = LDG(f + 64 + lane);
  while (!__all((int)(a >= e && b >= e))){
    __builtin_amdgcn_s_sleep(2);
    a = LDG(f + lane); b = LDG(f + 64 + lane);
  }
}

// zone float index: slot = m*8 + ks*2 + nt, lane; 16 slots x 64 lanes x f32x4 = 16 KB
#define ZI(slot, ln) (((slot) * 64 + (ln)) * 4)

// ======================= layer 0 =======================
__device__ void run_l0(int bid_l,
    const int* __restrict__ inputs, const float* __restrict__ c0,
    const us* __restrict__ emb_bf,
    const float* __restrict__ Wih0, const float* __restrict__ Whh0,
    const us* __restrict__ h0ic, us* __restrict__ hist0,
    float* __restrict__ hn, float* __restrict__ cn,
    unsigned* __restrict__ f0A, unsigned* __restrict__ f0B, float* zone)
{
  const int tid = threadIdx.x, lane = tid & 63, wid = tid >> 6;
  const int l16 = lane & 15, hi = lane >> 4, kq = hi << 3;
  const int ks = wid;                     // K-quarter
  const int j0 = bid_l * 8;

  // ---- weights (identical layout to R6) ----
  bf16x8 wx[2][4], wh[2][8];
  #pragma unroll
  for (int m = 0; m < 2; ++m){
    const int g = l16 & 3, u = 2 * (l16 >> 2) + m;
    const float* rx = Wih0 + (size_t)(g * HH + j0 + u) * EE;
    const float* rh = Whh0 + (size_t)(g * HH + j0 + u) * HH;
    #pragma unroll
    for (int kk = 0; kk < 4; ++kk){
      int k0 = ks * 128 + kk * 32 + kq;
      wx[m][kk] = pack8(*(const float4*)(rx + k0), *(const float4*)(rx + k0 + 4));
    }
    #pragma unroll
    for (int kk = 0; kk < 8; ++kk){
      int k0 = ks * 256 + kk * 32 + kq;
      wh[m][kk] = pack8(*(const float4*)(rh + k0), *(const float4*)(rh + k0 + 4));
    }
  }

  // thread owns batch b_own = wid*16+l16, units j0+2hi, +1; active in half (wid>>1)
  const int b_own = wid * 16 + l16;
  const int myhalf = wid >> 1;
  const int ntb = wid & 1;
  float cs[2];
  #pragma unroll
  for (int m = 0; m < 2; ++m) cs[m] = c0[(size_t)b_own * HH + j0 + 2 * hi + m];

  f32x4 acc[2][2];

  for (int t = 0; t < TT; ++t){
    // ================= half A (p=0) =================
    #pragma unroll
    for (int m = 0; m < 2; ++m){ acc[m][0]=(f32x4){0,0,0,0}; acc[m][1]=(f32x4){0,0,0,0}; }
    {
      const us* xr0 = emb_bf + (size_t)inputs[t * BB + l16] * EE;
      const us* xr1 = emb_bf + (size_t)inputs[t * BB + 16 + l16] * EE;
      #pragma unroll
      for (int kk = 0; kk < 4; ++kk){
        const int kb = ks * 128 + kk * 32 + kq;
        bf16x8 b0 = *(const bf16x8*)(xr0 + kb);
        bf16x8 b1 = *(const bf16x8*)(xr1 + kb);
        acc[0][0] = MFMA(wx[0][kk], b0, acc[0][0]);
        acc[1][0] = MFMA(wx[1][kk], b0, acc[1][0]);
        acc[0][1] = MFMA(wx[0][kk], b1, acc[0][1]);
        acc[1][1] = MFMA(wx[1][kk], b1, acc[1][1]);
      }
    }
    if (t > 0){   // drain B(t-1) stores (hidden under emb), raise f0B = t
      asm volatile("s_waitcnt vmcnt(0)" ::: "memory");
      __syncthreads();
      if (tid == 0) __hip_atomic_store(f0B + bid_l, (unsigned)t, __ATOMIC_RELAXED, __HIP_MEMORY_SCOPE_AGENT);
      wait128(f0A, (unsigned)t, lane);
    }
    {
      const us* hs = (t == 0) ? h0ic : hist0 + (size_t)(t - 1) * BBHH;
      #pragma unroll
      for (int kk = 0; kk < 8; ++kk){
        const us* q = hs + (size_t)(ks * 32 + kk * 4 + hi) * 512;
        bf16x8 b0 = *(const bf16x8*)(q + l16 * 8);
        bf16x8 b1 = *(const bf16x8*)(q + 128 + l16 * 8);
        acc[0][0] = MFMA(wh[0][kk], b0, acc[0][0]);
        acc[1][0] = MFMA(wh[1][kk], b0, acc[1][0]);
        acc[0][1] = MFMA(wh[0][kk], b1, acc[0][1]);
        acc[1][1] = MFMA(wh[1][kk], b1, acc[1][1]);
      }
    }
    #pragma unroll
    for (int m = 0; m < 2; ++m)
      #pragma unroll
      for (int nt = 0; nt < 2; ++nt)
        *(f32x4*)&zone[ZI(m * 8 + ks * 2 + nt, lane)] = acc[m][nt];
    __syncthreads();
    if (myhalf == 0){
      f32x4 s[2];
      #pragma unroll
      for (int m = 0; m < 2; ++m){
        s[m] = (f32x4){0,0,0,0};
        #pragma unroll
        for (int kr = 0; kr < 4; ++kr)
          s[m] += *(f32x4*)&zone[ZI(m * 8 + kr * 2 + ntb, hi * 16 + l16)];
      }
      float hv[2];
      #pragma unroll
      for (int m = 0; m < 2; ++m){
        float gi = sigmoidf_(s[m][0]), gf = sigmoidf_(s[m][1]);
        float gg = tanhf_(s[m][2]),    go = sigmoidf_(s[m][3]);
        cs[m] = gf * cs[m] + gi * gg;
        hv[m] = go * tanhf_(cs[m]);
      }
      unsigned w = (unsigned)f2b(hv[0]) | ((unsigned)f2b(hv[1]) << 16);
      __hip_atomic_store((unsigned*)(hist0 + (size_t)t * BBHH + ((size_t)bid_l * BB + b_own) * 8 + 2 * hi),
                         w, __ATOMIC_RELAXED, __HIP_MEMORY_SCOPE_AGENT);
      if (t == TT - 1){
        size_t o = (size_t)b_own * HH + j0 + 2 * hi;
        *reinterpret_cast<float2*>(hn + o) = make_float2(hv[0], hv[1]);
        *reinterpret_cast<float2*>(cn + o) = make_float2(cs[0], cs[1]);
      }
    }

    // ================= half B (p=1) =================
    #pragma unroll
    for (int m = 0; m < 2; ++m){ acc[m][0]=(f32x4){0,0,0,0}; acc[m][1]=(f32x4){0,0,0,0}; }
    {
      const us* xr0 = emb_bf + (size_t)inputs[t * BB + 32 + l16] * EE;
      const us* xr1 = emb_bf + (size_t)inputs[t * BB + 48 + l16] * EE;
      #pragma unroll
      for (int kk = 0; kk < 4; ++kk){
        const int kb = ks * 128 + kk * 32 + kq;
        bf16x8 b0 = *(const bf16x8*)(xr0 + kb);
        bf16x8 b1 = *(const bf16x8*)(xr1 + kb);
        acc[0][0] = MFMA(wx[0][kk], b0, acc[0][0]);
        acc[1][0] = MFMA(wx[1][kk], b0, acc[1][0]);
        acc[0][1] = MFMA(wx[0][kk], b1, acc[0][1]);
        acc[1][1] = MFMA(wx[1][kk], b1, acc[1][1]);
      }
    }
    {   // drain A(t) stores (hidden under emb), raise f0A = t+1
      asm volatile("s_waitcnt vmcnt(0)" ::: "memory");
      __syncthreads();
      if (tid == 0) __hip_atomic_store(f0A + bid_l, (unsigned)(t + 1), __ATOMIC_RELAXED, __HIP_MEMORY_SCOPE_AGENT);
    }
    if (t > 0) wait128(f0B, (unsigned)t, lane);
    {
      const us* hs = (t == 0) ? h0ic : hist0 + (size_t)(t - 1) * BBHH;
      #pragma unroll
      for (int kk = 0; kk < 8; ++kk){
        const us* q = hs + (size_t)(ks * 32 + kk * 4 + hi) * 512 + 256;
        bf16x8 b0 = *(const bf16x8*)(q + l16 * 8);
        bf16x8 b1 = *(const bf16x8*)(q + 128 + l16 * 8);
        acc[0][0] = MFMA(wh[0][kk], b0, acc[0][0]);
        acc[1][0] = MFMA(wh[1][kk], b0, acc[1][0]);
        acc[0][1] = MFMA(wh[0][kk], b1, acc[0][1]);
        acc[1][1] = MFMA(wh[1][kk], b1, acc[1][1]);
      }
    }
    #pragma unroll
    for (int m = 0; m < 2; ++m)
      #pragma unroll
      for (int nt = 0; nt < 2; ++nt)
        *(f32x4*)&zone[ZI(m * 8 + ks * 2 + nt, lane)] = acc[m][nt];
    __syncthreads();
    if (myhalf == 1){
      f32x4 s[2];
      #pragma unroll
      for (int m = 0; m < 2; ++m){
        s[m] = (f32x4){0,0,0,0};
        #pragma unroll
        for (int kr = 0; kr < 4; ++kr)
          s[m] += *(f32x4*)&zone[ZI(m * 8 + kr * 2 + ntb, hi * 16 + l16)];
      }
      float hv[2];
      #pragma unroll
      for (int m = 0; m < 2; ++m){
        float gi = sigmoidf_(s[m][0]), gf = sigmoidf_(s[m][1]);
        float gg = tanhf_(s[m][2]),    go = sigmoidf_(s[m][3]);
        cs[m] = gf * cs[m] + gi * gg;
        hv[m] = go * tanhf_(cs[m]);
      }
      unsigned w = (unsigned)f2b(hv[0]) | ((unsigned)f2b(hv[1]) << 16);
      __hip_atomic_store((unsigned*)(hist0 + (size_t)t * BBHH + ((size_t)bid_l * BB + b_own) * 8 + 2 * hi),
                         w, __ATOMIC_RELAXED, __HIP_MEMORY_SCOPE_AGENT);
      if (t == TT - 1){
        size_t o = (size_t)b_own * HH + j0 + 2 * hi;
        *reinterpret_cast<float2*>(hn + o) = make_float2(hv[0], hv[1]);
        *reinterpret_cast<float2*>(cn + o) = make_float2(cs[0], cs[1]);
      }
    }
  }
  asm volatile("s_waitcnt vmcnt(0)" ::: "memory");
  __syncthreads();
  if (tid == 0) __hip_atomic_store(f0B + bid_l, (unsigned)TT, __ATOMIC_RELAXED, __HIP_MEMORY_SCOPE_AGENT);
}

// ======================= layer 1 =======================
__device__ void run_l1(int bid_l,
    const float* __restrict__ c0,
    const float* __restrict__ Wih1, const float* __restrict__ Whh1,
    const us* __restrict__ h1ic, const us* __restrict__ hist0, us* __restrict__ hist1,
    const float* __restrict__ decW, const float* __restrict__ decb,
    float* __restrict__ dec_out, float* __restrict__ hn, float* __restrict__ cn,
    unsigned* __restrict__ f0A, unsigned* __restrict__ f0B,
    unsigned* __restrict__ f1A, unsigned* __restrict__ f1B, float* zone)
{
  const int tid = threadIdx.x, lane = tid & 63, wid = tid >> 6;
  const int l16 = lane & 15, hi = lane >> 4, kq = hi << 3;
  const int ks = wid;
  const int j0 = bid_l * 8;

  bf16x8 wx[2][8], wh[2][8];
  #pragma unroll
  for (int m = 0; m < 2; ++m){
    const int g = l16 & 3, u = 2 * (l16 >> 2) + m;
    const float* rx = Wih1 + (size_t)(g * HH + j0 + u) * HH;
    const float* rh = Whh1 + (size_t)(g * HH + j0 + u) * HH;
    #pragma unroll
    for (int kk = 0; kk < 8; ++kk){
      int k0 = ks * 256 + kk * 32 + kq;
      wx[m][kk] = pack8(*(const float4*)(rx + k0), *(const float4*)(rx + k0 + 4));
      wh[m][kk] = pack8(*(const float4*)(rh + k0), *(const float4*)(rh + k0 + 4));
    }
  }

  const int b_own = wid * 16 + l16;
  const int myhalf = wid >> 1;
  const int ntb = wid & 1;
  float cs[2];
  #pragma unroll
  for (int m = 0; m < 2; ++m) cs[m] = c0[(size_t)BBHH + (size_t)b_own * HH + j0 + 2 * hi + m];
  float pooldec = 0.f;
  const float dw0 = decW[j0 + 2 * hi], dw1 = decW[j0 + 2 * hi + 1];

  f32x4 acc[2][2];

  for (int t = 0; t < TT; ++t){
    // ================= half A =================
    wait128(f0A, (unsigned)(t + 1), lane);
    #pragma unroll
    for (int m = 0; m < 2; ++m){ acc[m][0]=(f32x4){0,0,0,0}; acc[m][1]=(f32x4){0,0,0,0}; }
    {
      const us* xs = hist0 + (size_t)t * BBHH;
      #pragma unroll
      for (int kk = 0; kk < 8; ++kk){
        const us* q = xs + (size_t)(ks * 32 + kk * 4 + hi) * 512;
        bf16x8 b0 = *(const bf16x8*)(q + l16 * 8);
        bf16x8 b1 = *(const bf16x8*)(q + 128 + l16 * 8);
        acc[0][0] = MFMA(wx[0][kk], b0, acc[0][0]);
        acc[1][0] = MFMA(wx[1][kk], b0, acc[1][0]);
        acc[0][1] = MFMA(wx[0][kk], b1, acc[0][1]);
        acc[1][1] = MFMA(wx[1][kk], b1, acc[1][1]);
      }
    }
    if (t > 0){   // drain B(t-1), raise f1B = t (hidden under x-part)
      asm volatile("s_waitcnt vmcnt(0)" ::: "memory");
      __syncthreads();
      if (tid == 0) __hip_atomic_store(f1B + bid_l, (unsigned)t, __ATOMIC_RELAXED, __HIP_MEMORY_SCOPE_AGENT);
      wait128(f1A, (unsigned)t, lane);
    }
    {
      const us* hs = (t == 0) ? h1ic : hist1 + (size_t)(t - 1) * BBHH;
      #pragma unroll
      for (int kk = 0; kk < 8; ++kk){
        const us* q = hs + (size_t)(ks * 32 + kk * 4 + hi) * 512;
        bf16x8 b0 = *(const bf16x8*)(q + l16 * 8);
        bf16x8 b1 = *(const bf16x8*)(q + 128 + l16 * 8);
        acc[0][0] = MFMA(wh[0][kk], b0, acc[0][0]);
        acc[1][0] = MFMA(wh[1][kk], b0, acc[1][0]);
        acc[0][1] = MFMA(wh[0][kk], b1, acc[0][1]);
        acc[1][1] = MFMA(wh[1][kk], b1, acc[1][1]);
      }
    }
    #pragma unroll
    for (int m = 0; m < 2; ++m)
      #pragma unroll
      for (int nt = 0; nt < 2; ++nt)
        *(f32x4*)&zone[ZI(m * 8 + ks * 2 + nt, lane)] = acc[m][nt];
    __syncthreads();
    if (myhalf == 0){
      f32x4 s[2];
      #pragma unroll
      for (int m = 0; m < 2; ++m){
        s[m] = (f32x4){0,0,0,0};
        #pragma unroll
        for (int kr = 0; kr < 4; ++kr)
          s[m] += *(f32x4*)&zone[ZI(m * 8 + kr * 2 + ntb, hi * 16 + l16)];
      }
      float hv[2];
      #pragma unroll
      for (int m = 0; m < 2; ++m){
        float gi = sigmoidf_(s[m][0]), gf = sigmoidf_(s[m][1]);
        float gg = tanhf_(s[m][2]),    go = sigmoidf_(s[m][3]);
        cs[m] = gf * cs[m] + gi * gg;
        hv[m] = go * tanhf_(cs[m]);
      }
      unsigned w = (unsigned)f2b(hv[0]) | ((unsigned)f2b(hv[1]) << 16);
      __hip_atomic_store((unsigned*)(hist1 + (size_t)t * BBHH + ((size_t)bid_l * BB + b_own) * 8 + 2 * hi),
                         w, __ATOMIC_RELAXED, __HIP_MEMORY_SCOPE_AGENT);
      pooldec += hv[0] * dw0 + hv[1] * dw1;
      if (t == TT - 1){
        size_t o = (size_t)BBHH + (size_t)b_own * HH + j0 + 2 * hi;
        *reinterpret_cast<float2*>(hn + o) = make_float2(hv[0], hv[1]);
        *reinterpret_cast<float2*>(cn + o) = make_float2(cs[0], cs[1]);
      }
    }

    // ================= half B =================
    wait128(f0B, (unsigned)(t + 1), lane);
    #pragma unroll
    for (int m = 0; m < 2; ++m){ acc[m][0]=(f32x4){0,0,0,0}; acc[m][1]=(f32x4){0,0,0,0}; }
    {
      const us* xs = hist0 + (size_t)t * BBHH;
      #pragma unroll
      for (int kk = 0; kk < 8; ++kk){
        const us* q = xs + (size_t)(ks * 32 + kk * 4 + hi) * 512 + 256;
        bf16x8 b0 = *(const bf16x8*)(q + l16 * 8);
        bf16x8 b1 = *(const bf16x8*)(q + 128 + l16 * 8);
        acc[0][0] = MFMA(wx[0][kk], b0, acc[0][0]);
        acc[1][0] = MFMA(wx[1][kk], b0, acc[1][0]);
        acc[0][1] = MFMA(wx[0][kk], b1, acc[0][1]);
        acc[1][1] = MFMA(wx[1][kk], b1, acc[1][1]);
      }
    }
    {   // drain A(t), raise f1A = t+1
      asm volatile("s_waitcnt vmcnt(0)" ::: "memory");
      __syncthreads();
      if (tid == 0) __hip_atomic_store(f1A + bid_l, (unsigned)(t + 1), __ATOMIC_RELAXED, __HIP_MEMORY_SCOPE_AGENT);
    }
    if (t > 0) wait128(f1B, (unsigned)t, lane);
    {
      const us* hs = (t == 0) ? h1ic : hist1 + (size_t)(t - 1) * BBHH;
      #pragma unroll
      for (int kk = 0; kk < 8; ++kk){
        const us* q = hs + (size_t)(ks * 32 + kk * 4 + hi) * 512 + 256;
        bf16x8 b0 = *(const bf16x8*)(q + l16 * 8);
        bf16x8 b1 = *(const bf16x8*)(q + 128 + l16 * 8);
        acc[0][0] = MFMA(wh[0][kk], b0, acc[0][0]);
        acc[1][0] = MFMA(wh[1][kk], b0, acc[1][0]);
        acc[0][1] = MFMA(wh[0][kk], b1, acc[0][1]);
        acc[1][1] = MFMA(wh[1][kk], b1, acc[1][1]);
      }
    }
    #pragma unroll
    for (int m = 0; m < 2; ++m)
      #pragma unroll
      for (int nt = 0; nt < 2; ++nt)
        *(f32x4*)&zone[ZI(m * 8 + ks * 2 + nt, lane)] = acc[m][nt];
    __syncthreads();
    if (myhalf == 1){
      f32x4 s[2];
      #pragma unroll
      for (int m = 0; m < 2; ++m){
        s[m] = (f32x4){0,0,0,0};
        #pragma unroll
        for (int kr = 0; kr < 4; ++kr)
          s[m] += *(f32x4*)&zone[ZI(m * 8 + kr * 2 + ntb, hi * 16 + l16)];
      }
      float hv[2];
      #pragma unroll
      for (int m = 0; m < 2; ++m){
        float gi = sigmoidf_(s[m][0]), gf = sigmoidf_(s[m][1]);
        float gg = tanhf_(s[m][2]),    go = sigmoidf_(s[m][3]);
        cs[m] = gf * cs[m] + gi * gg;
        hv[m] = go * tanhf_(cs[m]);
      }
      unsigned w = (unsigned)f2b(hv[0]) | ((unsigned)f2b(hv[1]) << 16);
      __hip_atomic_store((unsigned*)(hist1 + (size_t)t * BBHH + ((size_t)bid_l * BB + b_own) * 8 + 2 * hi),
                         w, __ATOMIC_RELAXED, __HIP_MEMORY_SCOPE_AGENT);
      pooldec += hv[0] * dw0 + hv[1] * dw1;
      if (t == TT - 1){
        size_t o = (size_t)BBHH + (size_t)b_own * HH + j0 + 2 * hi;
        *reinterpret_cast<float2*>(hn + o) = make_float2(hv[0], hv[1]);
        *reinterpret_cast<float2*>(cn + o) = make_float2(cs[0], cs[1]);
      }
    }
  }

  // ---- decode: sum over hi (units) within wave, one atomic per (b) ----
  pooldec += __shfl_xor(pooldec, 16);
  pooldec += __shfl_xor(pooldec, 32);
  if (hi == 0){
    float contrib = pooldec * (1.0f / (float)TT);
    if (bid_l == 0) contrib += decb[0];
    atomicAdd(&dec_out[b_own], contrib);
  }
}

__global__ __launch_bounds__(256, 1) void lstm_persist(
    const int* __restrict__ inputs, const float* __restrict__ c0,
    const us* __restrict__ emb_bf,
    const float* __restrict__ Wih0, const float* __restrict__ Whh0,
    const float* __restrict__ Wih1, const float* __restrict__ Whh1,
    const us* __restrict__ h0ic, const us* __restrict__ h1ic,
    us* __restrict__ hist0, us* __restrict__ hist1,
    const float* __restrict__ decW, const float* __restrict__ decb,
    float* __restrict__ dec_out, float* __restrict__ hn, float* __restrict__ cn,
    unsigned* __restrict__ flags)
{
  __shared__ float zone[16 * 64 * 4];   // 16 KB
  unsigned* f0A = flags;
  unsigned* f0B = flags + 128;
  unsigned* f1A = flags + 256;
  unsigned* f1B = flags + 384;
  int bid = blockIdx.x;
  if (bid < NBL){
    run_l0(bid, inputs, c0, emb_bf, Wih0, Whh0, h0ic, hist0,
           hn, cn, f0A, f0B, zone);
  } else {
    run_l1(bid - NBL, c0, Wih1, Whh1, h1ic, hist0, hist1, decW, decb,
           dec_out, hn, cn, f0A, f0B, f1A, f1B, zone);
  }
}

extern "C" void kernel_launch(void* const* d_in, const int* in_sizes, int n_in,
                              void* d_out, int out_size, void* d_ws, size_t ws_size,
                              hipStream_t stream){
  const int*   inputs = (const int*)d_in[0];
  const float* h0     = (const float*)d_in[1];
  const float* c0     = (const float*)d_in[2];
  const float* emb    = (const float*)d_in[3];
  const float* Wih0   = (const float*)d_in[4];
  const float* Whh0   = (const float*)d_in[5];
  const float* Wih1   = (const float*)d_in[6];
  const float* Whh1   = (const float*)d_in[7];
  const float* decW   = (const float*)d_in[8];
  const float* decb   = (const float*)d_in[9];

  char* ws = (char*)d_ws;
  size_t off = 0;
  auto alloc = [&](size_t bytes) -> void* {
    void* p = ws + off;
    off += (bytes + 255) & ~(size_t)255;
    return p;
  };
  us* emb_bf = (us*)alloc((size_t)VV * EE * 2);        // 51.2 MB
  us* hist0  = (us*)alloc((size_t)TT * BBHH * 2);      // 64 MB
  us* hist1  = (us*)alloc((size_t)TT * BBHH * 2);      // 64 MB
  us* h0ic   = (us*)alloc((size_t)BBHH * 2);
  us* h1ic   = (us*)alloc((size_t)BBHH * 2);
  unsigned* flags = (unsigned*)alloc((size_t)512 * 4);

  float* out = (float*)d_out;            // decoded [B]
  float* hn  = out + BB;                 // [2,B,H]
  float* cn  = out + BB + 2 * BBHH;      // [2,B,H]

  hipMemsetAsync(flags, 0, 512 * 4, stream);
  hipMemsetAsync(out, 0, BB * 4, stream);

  cast_f2b<<<2048, 256, 0, stream>>>(emb, emb_bf, (long)VV * EE);
  init_h<<<BBHH / 256, 256, 0, stream>>>(h0, h0ic, h1ic);

  lstm_persist<<<NBLK, 256, 0, stream>>>(inputs, c0, emb_bf,
                                         Wih0, Whh0, Wih1, Whh1,
                                         h0ic, h1ic, hist0, hist1,
                                         decW, decb, out, hn, cn, flags);
}